// Round 14
// baseline (673.751 us; speedup 1.0000x reference)
//
#include <hip/hip_runtime.h>

#define B_ 256
#define T_ 2048
#define H_ 64

typedef float f32x4 __attribute__((ext_vector_type(4)));
typedef _Float16 h16x2 __attribute__((ext_vector_type(2)));

__device__ __forceinline__ float fdot2(h16x2 a, h16x2 b, float c) {
#if __has_builtin(__builtin_amdgcn_fdot2)
    return __builtin_amdgcn_fdot2(a, b, c, false);   // v_dot2_f32_f16
#else
    float d;
    asm("v_dot2_f32_f16 %0, %1, %2, %3" : "=v"(d) : "v"(a), "v"(b), "v"(c));
    return d;
#endif
}

__device__ __forceinline__ float readlane_f(float v, int idx) {
    return __builtin_bit_cast(float,
        __builtin_amdgcn_readlane(__builtin_bit_cast(int, v), idx));
}

#define NLOG2E (-1.4426950408889634f)   // -log2(e): sigmoid prescale
#define TLOG2E ( 2.8853900817779268f)   // 2*log2(e): tanh prescale

// Single wave per batch row, ZERO LDS. R2-R13 all paid a ~150-cyc LDS
// round trip (ds_write -> lgkmcnt -> 8x ds_read) per step to rebroadcast h.
// Replaced with pure register lane ops:
//   h_new (1 chan/lane, fp32) -> v_cvt_f16 -> DPP quad_perm [1,0,3,2]
//   (lane^1 neighbor, full-rate VALU) -> pack u32 word on even lanes
//   -> 32 v_readlane into SGPRs (channel-pair words, wave-uniform)
// Each v_dot2_f32_f16 consumes its h-pair as the one legal SGPR operand:
// no LDS, no lgkmcnt, no barrier; exchange latency ~10 cyc.
// Gate-ordered dots (r -> z -> n) keep each sigmoid's latency hidden under
// the next gate's dot issue. Weights: f16 prescaled (exp2 factors folded),
// resident via launder.
__global__ __launch_bounds__(64, 1)
void gru_kernel(const float* __restrict__ x,
                const float* __restrict__ W_ih,
                const float* __restrict__ W_hh,
                const float* __restrict__ b_ih,
                const float* __restrict__ b_hh,
                float* __restrict__ out)
{
    const int lane = threadIdx.x;
    const int b    = blockIdx.x;

    // ---- preload W_hh rows {lane, 64+lane, 128+lane}, prescale, cvt f16 ----
    h16x2 wr[32], wz[32], wn[32];
    {
        const f32x4* pr = (const f32x4*)(W_hh + (size_t)lane * H_);
        const f32x4* pz = (const f32x4*)(W_hh + (size_t)(64 + lane) * H_);
        const f32x4* pn = (const f32x4*)(W_hh + (size_t)(128 + lane) * H_);
        #pragma unroll
        for (int q = 0; q < 16; ++q) {
            f32x4 vr = pr[q], vz = pz[q], vn = pn[q];
            wr[2*q]   = h16x2{(_Float16)(NLOG2E * vr.x), (_Float16)(NLOG2E * vr.y)};
            wr[2*q+1] = h16x2{(_Float16)(NLOG2E * vr.z), (_Float16)(NLOG2E * vr.w)};
            wz[2*q]   = h16x2{(_Float16)(NLOG2E * vz.x), (_Float16)(NLOG2E * vz.y)};
            wz[2*q+1] = h16x2{(_Float16)(NLOG2E * vz.z), (_Float16)(NLOG2E * vz.w)};
            wn[2*q]   = h16x2{(_Float16)(TLOG2E * vn.x), (_Float16)(TLOG2E * vn.y)};
            wn[2*q+1] = h16x2{(_Float16)(TLOG2E * vn.z), (_Float16)(TLOG2E * vn.w)};
        }
    }
    #pragma unroll
    for (int i = 0; i < 32; ++i)
        asm volatile("" : "+v"(wr[i]), "+v"(wz[i]), "+v"(wn[i]));

    // x-side params, prescaled
    const float wihr = NLOG2E * W_ih[lane];
    const float wihz = NLOG2E * W_ih[64 + lane];
    const float wihn = TLOG2E * W_ih[128 + lane];
    const float br   = NLOG2E * (b_ih[lane]      + b_hh[lane]);
    const float bz   = NLOG2E * (b_ih[64 + lane] + b_hh[64 + lane]);
    const float bhn  = TLOG2E * b_hh[128 + lane];
    const float bin  = TLOG2E * b_ih[128 + lane];

    const float* __restrict__ xrow = x + (size_t)b * T_;
    float* __restrict__ orow = out + (size_t)b * T_;

    float h_own = 0.0f;
    int   word  = 0;                 // packed f16 pair (chans 2i,2i+1) on even lanes
    float oval  = 0.0f;
    float xa = xrow[lane];           // current 64-step block of x
    float xb = 0.0f;

    for (int tb = 0; tb < T_ / 64; ++tb) {
        if (tb < T_ / 64 - 1) xb = xrow[(tb + 1) * 64 + lane];

        #pragma unroll 4
        for (int t2 = 0; t2 < 64; ++t2) {
            const float xt  = readlane_f(xa, t2);
            const float xpr = fmaf(xt, wihr, br);
            const float xpz = fmaf(xt, wihz, bz);
            const float xpn = fmaf(xt, wihn, bin);

            // ---- broadcast h: 32 readlanes -> SGPR channel-pair words ----
            h16x2 hv[32];
            #pragma unroll
            for (int i = 0; i < 32; ++i) {
                int wi = __builtin_amdgcn_readlane(word, 2 * i);
                hv[i] = __builtin_bit_cast(h16x2, wi);
            }

            // ---- r-gate first: sigmoid hides under z/n dot issue ----
            float ar[4] = {0.f, 0.f, 0.f, 0.f};
            #pragma unroll
            for (int i = 0; i < 32; ++i) ar[i & 3] = fdot2(wr[i], hv[i], ar[i & 3]);
            float sr = ((ar[0] + ar[1]) + (ar[2] + ar[3])) + xpr;
            float r  = __builtin_amdgcn_rcpf(1.0f + __builtin_amdgcn_exp2f(sr));

            // ---- z-gate ----
            float az[4] = {0.f, 0.f, 0.f, 0.f};
            #pragma unroll
            for (int i = 0; i < 32; ++i) az[i & 3] = fdot2(wz[i], hv[i], az[i & 3]);
            float sz = ((az[0] + az[1]) + (az[2] + az[3])) + xpz;
            float z  = __builtin_amdgcn_rcpf(1.0f + __builtin_amdgcn_exp2f(sz));

            // ---- n-gate ----
            float an[4] = {0.f, 0.f, 0.f, 0.f};
            #pragma unroll
            for (int i = 0; i < 32; ++i) an[i & 3] = fdot2(wn[i], hv[i], an[i & 3]);
            float hn  = ((an[0] + an[1]) + (an[2] + an[3])) + bhn;
            float pre = fmaf(r, hn, xpn);
            float n   = fmaf(-2.0f, __builtin_amdgcn_rcpf(
                              1.0f + __builtin_amdgcn_exp2f(pre)), 1.0f);

            float h_new = fmaf(z, h_own - n, n);   // (1-z)*n + z*h
            h_own = h_new;

            // ---- repack broadcast word for next step (pure VALU) ----
            {
                _Float16 hf = (_Float16)h_new;
                int own = (int)(unsigned int)__builtin_bit_cast(unsigned short, hf);
                int nbr = __builtin_amdgcn_mov_dpp(own, 0xB1, 0xF, 0xF, false);
                word = own | (nbr << 16);          // even lanes: (h2i | h2i+1<<16)
            }

            // output latch (off critical path)
            float h63 = readlane_f(h_new, 63);
            oval = (t2 == lane) ? h63 : oval;
        }

        orow[tb * 64 + lane] = oval;               // coalesced 256B store
        xa = xb;
    }
}

extern "C" void kernel_launch(void* const* d_in, const int* in_sizes, int n_in,
                              void* d_out, int out_size, void* d_ws, size_t ws_size,
                              hipStream_t stream) {
    const float* x    = (const float*)d_in[0];
    const float* W_ih = (const float*)d_in[1];
    const float* W_hh = (const float*)d_in[2];
    const float* b_ih = (const float*)d_in[3];
    const float* b_hh = (const float*)d_in[4];
    float* out = (float*)d_out;

    dim3 grid(B_), block(64);
    gru_kernel<<<grid, block, 0, stream>>>(x, W_ih, W_hh, b_ih, b_hh, out);
}